// Round 8
// baseline (285.739 us; speedup 1.0000x reference)
//
#include <hip/hip_runtime.h>
#include <stdint.h>

typedef __attribute__((ext_vector_type(8))) short short8;
typedef __attribute__((ext_vector_type(4))) short short4v;
typedef __attribute__((ext_vector_type(4))) float float4v;
typedef __attribute__((ext_vector_type(2))) uint32_t uint32x2;
typedef __attribute__((ext_vector_type(4))) uint32_t uint32x4;

__device__ __forceinline__ unsigned short f2bf(float f) {
  union { float f; uint32_t u; } v;
  v.f = f;
  uint32_t u = v.u;
  return (unsigned short)((u + 0x7fffu + ((u >> 16) & 1u)) >> 16);
}

__device__ __forceinline__ uint32_t pkbf(float a, float b) {
#if __has_builtin(__builtin_amdgcn_cvt_pk_bf16_f32)
  typedef __attribute__((ext_vector_type(2))) __bf16 bf16x2;
  bf16x2 r = __builtin_amdgcn_cvt_pk_bf16_f32(a, b);
  union { bf16x2 v; uint32_t u; } c;
  c.v = r;
  return c.u;
#else
  return (uint32_t)f2bf(a) | ((uint32_t)f2bf(b) << 16);
#endif
}

__device__ __forceinline__ float fexp2(float x) {
#if __has_builtin(__builtin_amdgcn_exp2f)
  return __builtin_amdgcn_exp2f(x);
#else
  return exp2f(x);
#endif
}

// K=16 bf16 MFMA (C-layout of prior MFMA == this B-operand layout).
__device__ __forceinline__ float4v mfma16bf(short4v a, short4v b, float4v c) {
#if __has_builtin(__builtin_amdgcn_mfma_f32_16x16x16bf16_1k)
  return __builtin_amdgcn_mfma_f32_16x16x16bf16_1k(a, b, c, 0, 0, 0);
#else
  float4v d;
  asm("v_mfma_f32_16x16x16_bf16 %0, %1, %2, %3"
      : "=v"(d) : "v"(a), "v"(b), "v"(c));
  return d;
#endif
}

__device__ __forceinline__ void gll16(const unsigned short* g, unsigned short* l) {
  __builtin_amdgcn_global_load_lds(
      (const __attribute__((address_space(1))) void*)g,
      (__attribute__((address_space(3))) void*)l, 16, 0, 0);
}

// ---------------------------------------------------------------------------
// One-shot fp32 -> bf16 conversion for all 7 tensors (coalesced, 16B stores).
// ---------------------------------------------------------------------------
struct CvtArgs {
  const float* src[7];
  unsigned short* dst[7];
};

__global__ __launch_bounds__(256) void cvt_all(CvtArgs a) {
  const int bid = blockIdx.x;
  int t, off;
  if (bid < 4608) { t = bid / 1536; off = bid - t * 1536; }
  else { const int b2 = bid - 4608; t = 3 + b2 / 288; off = b2 - (t - 3) * 288; }
  const size_t i = (size_t)off * 256 + threadIdx.x;
  const float4v* p = (const float4v*)(a.src[t] + i * 8);
  float4v x = p[0], y = p[1];
  uint32x4 o;
  o[0] = pkbf(x[0], x[1]);
  o[1] = pkbf(x[2], x[3]);
  o[2] = pkbf(y[0], y[1]);
  o[3] = pkbf(y[2], y[3]);
  *(uint32x4*)(a.dst[t] + i * 8) = o;
}

// ---------------------------------------------------------------------------
// Fused QKV projection, all-bf16, DMA staging into XOR-swizzled LDS.
// 128x128 tile, BK=64. z=0 -> Qp (scaled), z=1 -> Kp, z=2 -> Vt [N][M].
// ---------------------------------------------------------------------------
__global__ __launch_bounds__(256) void gemm_qkv(
    const unsigned short* __restrict__ xq, const unsigned short* __restrict__ xk,
    const unsigned short* __restrict__ xv,
    const unsigned short* __restrict__ wqb, const unsigned short* __restrict__ wkb,
    const unsigned short* __restrict__ wvb,
    const float* __restrict__ bq, const float* __restrict__ bk,
    const float* __restrict__ bv,
    unsigned short* __restrict__ Qp, unsigned short* __restrict__ Kp,
    unsigned short* __restrict__ Vt, float qscale)
{
  __shared__ unsigned short As[128 * 64];
  __shared__ unsigned short Ws[128 * 64];
  const int z = blockIdx.z;
  const unsigned short* A = z == 0 ? xq : z == 1 ? xk : xv;
  const unsigned short* W = z == 0 ? wqb : z == 1 ? wkb : wvb;
  const float* bias = z == 0 ? bq : z == 1 ? bk : bv;
  const int M = 4096, N = 768, K = 768;
  const int tid = threadIdx.x, wave = tid >> 6, lane = tid & 63;
  const int g = lane >> 4, l16 = lane & 15;
  const int sw = l16 & 7;
  const int m0 = blockIdx.x * 128, n0 = blockIdx.y * 128;
  const int wn = (wave >> 1) * 64, wm = (wave & 1) * 64;
  const int srow0 = wave * 32 + (lane >> 3);
  const int skg = lane & 7;

  float4v acc[4][4] = {};

  for (int k0 = 0; k0 < K; k0 += 64) {
    if (k0) __syncthreads();
    #pragma unroll
    for (int c = 0; c < 4; ++c) {
      const int row = srow0 + c * 8;
      const int kg = skg ^ (row & 7);
      gll16(A + (size_t)(m0 + row) * K + k0 + kg * 8, &As[(wave * 32 + c * 8) * 64]);
      gll16(W + (size_t)(n0 + row) * K + k0 + kg * 8, &Ws[(wave * 32 + c * 8) * 64]);
    }
    __syncthreads();
    #pragma unroll
    for (int kk = 0; kk < 2; ++kk) {
      const int kg = ((kk * 4 + g) ^ sw) * 8;
      short8 xf[4], wf[4];
      #pragma unroll
      for (int t = 0; t < 4; ++t) {
        xf[t] = *(const short8*)&As[(wm + t * 16 + l16) * 64 + kg];
        wf[t] = *(const short8*)&Ws[(wn + t * 16 + l16) * 64 + kg];
      }
      if (z < 2) {
        #pragma unroll
        for (int i = 0; i < 4; ++i)
          #pragma unroll
          for (int j = 0; j < 4; ++j)
            acc[i][j] = __builtin_amdgcn_mfma_f32_16x16x32_bf16(wf[i], xf[j], acc[i][j], 0, 0, 0);
      } else {
        #pragma unroll
        for (int i = 0; i < 4; ++i)
          #pragma unroll
          for (int j = 0; j < 4; ++j)
            acc[i][j] = __builtin_amdgcn_mfma_f32_16x16x32_bf16(xf[i], wf[j], acc[i][j], 0, 0, 0);
      }
    }
  }

  if (z < 2) {
    unsigned short* O = z == 0 ? Qp : Kp;
    const float osc = z == 0 ? qscale : 1.0f;
    #pragma unroll
    for (int i = 0; i < 4; ++i) {
      const int nb = n0 + wn + i * 16 + 4 * g;
      const float4v bb = *(const float4v*)&bias[nb];
      #pragma unroll
      for (int j = 0; j < 4; ++j) {
        const int m = m0 + wm + j * 16 + l16;
        uint32x2 pk;
        pk[0] = pkbf((acc[i][j][0] + bb[0]) * osc, (acc[i][j][1] + bb[1]) * osc);
        pk[1] = pkbf((acc[i][j][2] + bb[2]) * osc, (acc[i][j][3] + bb[3]) * osc);
        *(uint32x2*)(O + (size_t)m * N + nb) = pk;
      }
    }
  } else {
    #pragma unroll
    for (int j = 0; j < 4; ++j) {
      const int n = n0 + wn + j * 16 + l16;
      const float bb = bias[n];
      #pragma unroll
      for (int i = 0; i < 4; ++i) {
        const int mb = m0 + wm + i * 16 + 4 * g;
        uint32x2 pk;
        pk[0] = pkbf(acc[i][j][0] + bb, acc[i][j][1] + bb);
        pk[1] = pkbf(acc[i][j][2] + bb, acc[i][j][3] + bb);
        *(uint32x2*)(Vt + (size_t)n * M + mb) = pk;
      }
    }
  }
}

// ---------------------------------------------------------------------------
// Flash attention PARTIAL kernel, chunk = 8 k-blocks. 1728 blocks, max 8
// serial iters each, 5 blocks/CU (32KB LDS). Partial slots prefix-indexed:
// per (h,t): nc = (t>>2)+1 chunks, base = h*144 + nc*(2*(t>>2)+(t&3)).
// PV: K=16 MFMA, P from registers; V via b128 full-slot loads (2-way banks,
// free) with g&1 half-select.
// ---------------------------------------------------------------------------
__global__ __launch_bounds__(256, 5) void flash_part(
    const unsigned short* __restrict__ Qp,  // [S][768] bf16, pre-scaled
    const unsigned short* __restrict__ Kp,  // [S][768] bf16
    const unsigned short* __restrict__ Vt,  // [768][S] bf16
    unsigned short* __restrict__ Opart,     // [1728 slots][128][64] bf16
    float* __restrict__ lpart)              // [1728 slots][128] fp32
{
  __shared__ unsigned short lds_k[2][64 * 64];
  __shared__ unsigned short lds_v[2][64 * 64];
  const int S = 4096, DM = 768;

  // gid -> (h, band, t, c): heavy bands first; 12 heads per level -> XCD mix.
  const int gid = blockIdx.x;
  const int h = gid % 12;
  int rem = gid / 12;                 // 0..143
  int band = 8;
  while (rem >= 4 * band) { rem -= 4 * band; --band; }
  const int t = (band - 1) * 4 + (rem & 3);
  const int c = rem >> 2;             // 0..band-1, full chunks first
  const int kb0 = c * 8;
  const int kbe = min(kb0 + 8, 2 * t + 2);

  const int tid = threadIdx.x, wave = tid >> 6, lane = tid & 63;
  const int g = lane >> 4, l16 = lane & 15;
  const int sw = l16 & 7;
  const int qbase = t * 128 + wave * 32;

  short8 qf[2][2];
  #pragma unroll
  for (int qc = 0; qc < 2; ++qc) {
    const unsigned short* qp = Qp + (size_t)(qbase + qc * 16 + l16) * DM + h * 64;
    qf[qc][0] = *(const short8*)(qp + g * 8);
    qf[qc][1] = *(const short8*)(qp + 32 + g * 8);
  }

  float4v o[2][4] = {};
  float lsum[2] = {0.0f, 0.0f};

  const int strow = wave * 16 + (lane >> 3);
  const int skg = lane & 7;

  #pragma unroll
  for (int cc = 0; cc < 2; ++cc) {
    const int row = strow + cc * 8;
    const int kg = skg ^ (row & 7);
    gll16(Kp + (size_t)(kb0 * 64 + row) * DM + h * 64 + kg * 8,
          &lds_k[0][(wave * 16 + cc * 8) * 64]);
    gll16(Vt + (size_t)(h * 64 + row) * S + kb0 * 64 + kg * 8,
          &lds_v[0][(wave * 16 + cc * 8) * 64]);
  }
  __syncthreads();

  for (int kb = kb0; kb < kbe; ++kb) {
    const int cur = kb & 1;
    if (kb + 1 < kbe) {
      const int nb = cur ^ 1;
      #pragma unroll
      for (int cc = 0; cc < 2; ++cc) {
        const int row = strow + cc * 8;
        const int kg = skg ^ (row & 7);
        gll16(Kp + (size_t)((kb + 1) * 64 + row) * DM + h * 64 + kg * 8,
              &lds_k[nb][(wave * 16 + cc * 8) * 64]);
        gll16(Vt + (size_t)(h * 64 + row) * S + (kb + 1) * 64 + kg * 8,
              &lds_v[nb][(wave * 16 + cc * 8) * 64]);
      }
    }
    const unsigned short* kc = lds_k[cur];
    const unsigned short* vc = lds_v[cur];

    // S^T = K * Q^T : 4 key-subtiles x 2 q-columns (K=32 MFMA)
    float4v sf[2][4];
    #pragma unroll
    for (int mt = 0; mt < 4; ++mt) {
      short8 ka0 = *(const short8*)&kc[(mt * 16 + l16) * 64 + ((0 + g) ^ sw) * 8];
      short8 ka1 = *(const short8*)&kc[(mt * 16 + l16) * 64 + ((4 + g) ^ sw) * 8];
      #pragma unroll
      for (int qc = 0; qc < 2; ++qc) {
        float4v a = {};
        a = __builtin_amdgcn_mfma_f32_16x16x32_bf16(ka0, qf[qc][0], a, 0, 0, 0);
        a = __builtin_amdgcn_mfma_f32_16x16x32_bf16(ka1, qf[qc][1], a, 0, 0, 0);
        sf[qc][mt] = a;
      }
    }

    if ((kb + 1) * 64 > qbase) {  // causal mask (only triggers in last chunk)
      #pragma unroll
      for (int qc = 0; qc < 2; ++qc) {
        const int q = qbase + qc * 16 + l16;
        #pragma unroll
        for (int mt = 0; mt < 4; ++mt)
          #pragma unroll
          for (int rr = 0; rr < 4; ++rr) {
            const int key = kb * 64 + mt * 16 + 4 * g + rr;
            sf[qc][mt][rr] = (key <= q) ? sf[qc][mt][rr] : -1e30f;
          }
      }
    }

    // p = exp2(s); pack straight into PV B-fragments (C-layout == B-layout)
    short4v pb[2][4];
    #pragma unroll
    for (int qc = 0; qc < 2; ++qc)
      #pragma unroll
      for (int mt = 0; mt < 4; ++mt) {
        float4v pe;
        #pragma unroll
        for (int rr = 0; rr < 4; ++rr) {
          pe[rr] = fexp2(sf[qc][mt][rr]);
          lsum[qc] += pe[rr];
        }
        union { uint32x2 u; short4v s; } cv;
        cv.u[0] = pkbf(pe[0], pe[1]);
        cv.u[1] = pkbf(pe[2], pe[3]);
        pb[qc][mt] = cv.s;
      }

    // O^T += V^T * P : b128 full-slot V loads (2-way banks), half-select g&1
    #pragma unroll
    for (int ms = 0; ms < 4; ++ms) {
      const int slot = ((2 * ms + (g >> 1)) ^ sw) * 8;
      #pragma unroll
      for (int dt = 0; dt < 4; ++dt) {
        short8 va8 = *(const short8*)&vc[(dt * 16 + l16) * 64 + slot];
        short4v va = (g & 1) ? __builtin_shufflevector(va8, va8, 4, 5, 6, 7)
                             : __builtin_shufflevector(va8, va8, 0, 1, 2, 3);
        o[0][dt] = mfma16bf(va, pb[0][ms], o[0][dt]);
        o[1][dt] = mfma16bf(va, pb[1][ms], o[1][dt]);
      }
    }

    __syncthreads();  // drain prefetch DMA + protect buffer reuse
  }

  // epilogue: unnormalized partial write
  const int slot = h * 144 + band * (2 * (band - 1) + (t & 3)) + c;
  unsigned short* ob = Opart + (size_t)slot * 8192;
  #pragma unroll
  for (int qc = 0; qc < 2; ++qc) {
    float L = lsum[qc];
    L += __shfl_xor(L, 16);
    L += __shfl_xor(L, 32);
    const int ql = wave * 32 + qc * 16 + l16;
    if (g == 0) lpart[slot * 128 + ql] = L;
    #pragma unroll
    for (int dt = 0; dt < 4; ++dt) {
      uint32x2 ov;
      ov[0] = pkbf(o[qc][dt][0], o[qc][dt][1]);
      ov[1] = pkbf(o[qc][dt][2], o[qc][dt][3]);
      *(uint32x2*)(ob + (size_t)ql * 64 + dt * 16 + 4 * g) = ov;
    }
  }
}

// ---------------------------------------------------------------------------
// Combine partials: AO[q][h*64+d] = sum_c Opart / sum_c lpart. Grid (32, 12).
// ---------------------------------------------------------------------------
__global__ __launch_bounds__(256) void flash_combine(
    const unsigned short* __restrict__ Opart, const float* __restrict__ lpart,
    unsigned short* __restrict__ AO)
{
  const int t = blockIdx.x, h = blockIdx.y;
  const int a = t >> 2;
  const int nc = a + 1;
  const int slot0 = h * 144 + nc * (2 * a + (t & 3));
  const int tid = threadIdx.x;
  const int qr = tid >> 2, dc = (tid & 3) * 16;
  #pragma unroll
  for (int it = 0; it < 2; ++it) {
    const int ql = it * 64 + qr;
    float acc[16];
    #pragma unroll
    for (int j = 0; j < 16; ++j) acc[j] = 0.0f;
    float lsum = 0.0f;
    for (int cc = 0; cc < nc; ++cc) {
      const int slot = slot0 + cc;
      lsum += lpart[slot * 128 + ql];
      const uint32x4* p = (const uint32x4*)(Opart + (size_t)slot * 8192 + ql * 64 + dc);
      uint32x4 w0 = p[0], w1 = p[1];
      #pragma unroll
      for (int j = 0; j < 4; ++j) {
        union { uint32_t u; float f; } lo, hi;
        lo.u = w0[j] << 16; hi.u = w0[j] & 0xffff0000u;
        acc[2 * j] += lo.f; acc[2 * j + 1] += hi.f;
        lo.u = w1[j] << 16; hi.u = w1[j] & 0xffff0000u;
        acc[8 + 2 * j] += lo.f; acc[8 + 2 * j + 1] += hi.f;
      }
    }
    const float inv = 1.0f / lsum;
    uint32x4 o0, o1;
    #pragma unroll
    for (int j = 0; j < 4; ++j) {
      o0[j] = pkbf(acc[2 * j] * inv, acc[2 * j + 1] * inv);
      o1[j] = pkbf(acc[8 + 2 * j] * inv, acc[8 + 2 * j + 1] * inv);
    }
    unsigned short* dst = AO + (size_t)(t * 128 + ql) * 768 + h * 64 + dc;
    *(uint32x4*)dst = o0;
    *(uint32x4*)(dst + 8) = o1;
  }
}

// ---------------------------------------------------------------------------
// Output projection: fp32 out = AO(bf16) * wo^T + bo. 128x128, all-DMA, C^T.
// ---------------------------------------------------------------------------
__global__ __launch_bounds__(256) void gemm_out(
    const unsigned short* __restrict__ A, const unsigned short* __restrict__ W,
    const float* __restrict__ bias, float* __restrict__ Out)
{
  __shared__ unsigned short As[128 * 64];
  __shared__ unsigned short Ws[128 * 64];
  const int N = 768, K = 768;
  const int tid = threadIdx.x, wave = tid >> 6, lane = tid & 63;
  const int g = lane >> 4, l16 = lane & 15;
  const int sw = l16 & 7;
  const int m0 = blockIdx.x * 128, n0 = blockIdx.y * 128;
  const int wn = (wave >> 1) * 64, wm = (wave & 1) * 64;
  const int srow0 = wave * 32 + (lane >> 3);
  const int skg = lane & 7;

  float4v acc[4][4] = {};

  for (int k0 = 0; k0 < K; k0 += 64) {
    if (k0) __syncthreads();
    #pragma unroll
    for (int c = 0; c < 4; ++c) {
      const int row = srow0 + c * 8;
      const int kg = skg ^ (row & 7);
      gll16(A + (size_t)(m0 + row) * K + k0 + kg * 8, &As[(wave * 32 + c * 8) * 64]);
      gll16(W + (size_t)(n0 + row) * K + k0 + kg * 8, &Ws[(wave * 32 + c * 8) * 64]);
    }
    __syncthreads();
    #pragma unroll
    for (int kk = 0; kk < 2; ++kk) {
      const int kg = ((kk * 4 + g) ^ sw) * 8;
      short8 xf[4], wf[4];
      #pragma unroll
      for (int t = 0; t < 4; ++t) {
        xf[t] = *(const short8*)&As[(wm + t * 16 + l16) * 64 + kg];
        wf[t] = *(const short8*)&Ws[(wn + t * 16 + l16) * 64 + kg];
      }
      #pragma unroll
      for (int i = 0; i < 4; ++i)
        #pragma unroll
        for (int j = 0; j < 4; ++j)
          acc[i][j] = __builtin_amdgcn_mfma_f32_16x16x32_bf16(wf[i], xf[j], acc[i][j], 0, 0, 0);
    }
  }

  #pragma unroll
  for (int i = 0; i < 4; ++i) {
    const int nb = n0 + wn + i * 16 + 4 * g;
    const float4v bb = *(const float4v*)&bias[nb];
    #pragma unroll
    for (int j = 0; j < 4; ++j) {
      const int m = m0 + wm + j * 16 + l16;
      float4v ov;
      #pragma unroll
      for (int rr = 0; rr < 4; ++rr) ov[rr] = acc[i][j][rr] + bb[rr];
      *(float4v*)(Out + (size_t)m * N + nb) = ov;
    }
  }
}

extern "C" void kernel_launch(void* const* d_in, const int* in_sizes, int n_in,
                              void* d_out, int out_size, void* d_ws, size_t ws_size,
                              hipStream_t stream) {
  const float* q  = (const float*)d_in[0];
  const float* k  = (const float*)d_in[1];
  const float* v  = (const float*)d_in[2];
  const float* wq = (const float*)d_in[3];
  const float* bq = (const float*)d_in[4];
  const float* wk = (const float*)d_in[5];
  const float* bk = (const float*)d_in[6];
  const float* wv = (const float*)d_in[7];
  const float* bv = (const float*)d_in[8];
  const float* wo = (const float*)d_in[9];
  const float* bo = (const float*)d_in[10];
  float* out = (float*)d_out;

  const int S = 4096, D = 768;
  unsigned short* Qp    = (unsigned short*)d_ws;
  unsigned short* Kp    = Qp  + (size_t)S * D;
  unsigned short* Vt    = Kp  + (size_t)S * D;
  unsigned short* AO    = Vt  + (size_t)S * D;
  unsigned short* xq    = AO  + (size_t)S * D;
  unsigned short* xk    = xq  + (size_t)S * D;
  unsigned short* xv    = xk  + (size_t)S * D;
  unsigned short* wqb   = xv  + (size_t)S * D;
  unsigned short* wkb   = wqb + (size_t)D * D;
  unsigned short* wvb   = wkb + (size_t)D * D;
  unsigned short* wob   = wvb + (size_t)D * D;
  unsigned short* Opart = wob + (size_t)D * D;            // 1728 * 8192 bf16 = 27.6 MB
  float*          lpart = (float*)(Opart + (size_t)1728 * 8192);  // 1728*128 f32

  CvtArgs ca;
  ca.src[0] = q;  ca.dst[0] = xq;
  ca.src[1] = k;  ca.dst[1] = xk;
  ca.src[2] = v;  ca.dst[2] = xv;
  ca.src[3] = wq; ca.dst[3] = wqb;
  ca.src[4] = wk; ca.dst[4] = wkb;
  ca.src[5] = wv; ca.dst[5] = wvb;
  ca.src[6] = wo; ca.dst[6] = wob;

  const float SC = 0.125f * 1.44269504089f;  // (1/sqrt(64)) * log2(e), folded into Q
  dim3 blk(256);
  cvt_all<<<dim3(5760), blk, 0, stream>>>(ca);
  gemm_qkv<<<dim3(32, 6, 3), blk, 0, stream>>>(xq, xk, xv, wqb, wkb, wvb,
                                               bq, bk, bv, Qp, Kp, Vt, SC);
  flash_part<<<dim3(1728), blk, 0, stream>>>(Qp, Kp, Vt, Opart, lpart);
  flash_combine<<<dim3(32, 12), blk, 0, stream>>>(Opart, lpart, AO);
  gemm_out<<<dim3(32, 6), blk, 0, stream>>>(AO, wob, bo, out);
}

// Round 9
// 217.070 us; speedup vs baseline: 1.3163x; 1.3163x over previous
//
#include <hip/hip_runtime.h>
#include <stdint.h>

typedef __attribute__((ext_vector_type(8))) short short8;
typedef __attribute__((ext_vector_type(4))) short short4v;
typedef __attribute__((ext_vector_type(4))) float float4v;
typedef __attribute__((ext_vector_type(2))) uint32_t uint32x2;
typedef __attribute__((ext_vector_type(4))) uint32_t uint32x4;

__device__ __forceinline__ unsigned short f2bf(float f) {
  union { float f; uint32_t u; } v;
  v.f = f;
  uint32_t u = v.u;
  return (unsigned short)((u + 0x7fffu + ((u >> 16) & 1u)) >> 16);
}

__device__ __forceinline__ uint32_t pkbf(float a, float b) {
#if __has_builtin(__builtin_amdgcn_cvt_pk_bf16_f32)
  typedef __attribute__((ext_vector_type(2))) __bf16 bf16x2;
  bf16x2 r = __builtin_amdgcn_cvt_pk_bf16_f32(a, b);
  union { bf16x2 v; uint32_t u; } c;
  c.v = r;
  return c.u;
#else
  return (uint32_t)f2bf(a) | ((uint32_t)f2bf(b) << 16);
#endif
}

__device__ __forceinline__ float fexp2(float x) {
#if __has_builtin(__builtin_amdgcn_exp2f)
  return __builtin_amdgcn_exp2f(x);
#else
  return exp2f(x);
#endif
}

// K=16 bf16 MFMA (C-layout of prior MFMA == this B-operand layout).
__device__ __forceinline__ float4v mfma16bf(short4v a, short4v b, float4v c) {
#if __has_builtin(__builtin_amdgcn_mfma_f32_16x16x16bf16_1k)
  return __builtin_amdgcn_mfma_f32_16x16x16bf16_1k(a, b, c, 0, 0, 0);
#else
  float4v d;
  asm("v_mfma_f32_16x16x16_bf16 %0, %1, %2, %3"
      : "=v"(d) : "v"(a), "v"(b), "v"(c));
  return d;
#endif
}

__device__ __forceinline__ void gll16(const unsigned short* g, unsigned short* l) {
  __builtin_amdgcn_global_load_lds(
      (const __attribute__((address_space(1))) void*)g,
      (__attribute__((address_space(3))) void*)l, 16, 0, 0);
}

// ---------------------------------------------------------------------------
// fp32 -> bf16 conversion for the 4 weight matrices only (288 blocks each).
// ---------------------------------------------------------------------------
struct CvtArgs {
  const float* src[4];
  unsigned short* dst[4];
};

__global__ __launch_bounds__(256) void cvt_all(CvtArgs a) {
  const int bid = blockIdx.x;
  const int t = bid / 288, off = bid - t * 288;
  const size_t i = (size_t)off * 256 + threadIdx.x;
  const float4v* p = (const float4v*)(a.src[t] + i * 8);
  float4v x = p[0], y = p[1];
  uint32x4 o;
  o[0] = pkbf(x[0], x[1]);
  o[1] = pkbf(x[2], x[3]);
  o[2] = pkbf(y[0], y[1]);
  o[3] = pkbf(y[2], y[3]);
  *(uint32x4*)(a.dst[t] + i * 8) = o;
}

// ---------------------------------------------------------------------------
// Fused QKV projection. A = fp32 input read DIRECTLY with 256B-granular
// coalesced staging (flat 16B-chunk index: 4 rows x 256B contiguous per load
// instruction -> 100% cacheline utilization), converted to bf16 into the
// XOR-swizzled LDS. W = bf16 via DMA. 128x128 tile, BK=64.
// z=0 -> Qp (scaled), z=1 -> Kp, z=2 -> Vt [N][M].
// ---------------------------------------------------------------------------
__global__ __launch_bounds__(256) void gemm_qkv(
    const float* __restrict__ xq, const float* __restrict__ xk,
    const float* __restrict__ xv,
    const unsigned short* __restrict__ wqb, const unsigned short* __restrict__ wkb,
    const unsigned short* __restrict__ wvb,
    const float* __restrict__ bq, const float* __restrict__ bk,
    const float* __restrict__ bv,
    unsigned short* __restrict__ Qp, unsigned short* __restrict__ Kp,
    unsigned short* __restrict__ Vt, float qscale)
{
  __shared__ unsigned short As[128 * 64];
  __shared__ unsigned short Ws[128 * 64];
  const int z = blockIdx.z;
  const float* A32 = z == 0 ? xq : z == 1 ? xk : xv;
  const unsigned short* W = z == 0 ? wqb : z == 1 ? wkb : wvb;
  const float* bias = z == 0 ? bq : z == 1 ? bk : bv;
  const int M = 4096, N = 768, K = 768;
  const int tid = threadIdx.x, wave = tid >> 6, lane = tid & 63;
  const int g = lane >> 4, l16 = lane & 15;
  const int sw = l16 & 7;
  const int m0 = blockIdx.x * 128, n0 = blockIdx.y * 128;
  const int wn = (wave >> 1) * 64, wm = (wave & 1) * 64;
  const int srow0 = wave * 32 + (lane >> 3);
  const int skg = lane & 7;

  float4v acc[4][4] = {};

  for (int k0 = 0; k0 < K; k0 += 64) {
    if (k0) __syncthreads();
    // W: bf16 DMA staging (4 x 1KB per wave)
    #pragma unroll
    for (int c = 0; c < 4; ++c) {
      const int row = srow0 + c * 8;
      const int kg = skg ^ (row & 7);
      gll16(W + (size_t)(n0 + row) * K + k0 + kg * 8, &Ws[(wave * 32 + c * 8) * 64]);
    }
    // A: fp32 coalesced load + cvt. flat 16B-chunk f = inst*256 + tid:
    // row = f>>4 (0..127), c = f&15 (16B fp32 chunk = 4 floats = 4 bf16).
    #pragma unroll
    for (int inst = 0; inst < 8; ++inst) {
      const int f = inst * 256 + tid;
      const int row = f >> 4, c = f & 15;
      float4v a = *(const float4v*)(A32 + (size_t)(m0 + row) * K + k0 + c * 4);
      uint32x2 pk;
      pk[0] = pkbf(a[0], a[1]);
      pk[1] = pkbf(a[2], a[3]);
      const int s = c >> 1;
      *(uint32x2*)&As[row * 64 + ((s ^ (row & 7)) * 8) + (c & 1) * 4] = pk;
    }
    __syncthreads();
    #pragma unroll
    for (int kk = 0; kk < 2; ++kk) {
      const int kg = ((kk * 4 + g) ^ sw) * 8;
      short8 xf[4], wf[4];
      #pragma unroll
      for (int t = 0; t < 4; ++t) {
        xf[t] = *(const short8*)&As[(wm + t * 16 + l16) * 64 + kg];
        wf[t] = *(const short8*)&Ws[(wn + t * 16 + l16) * 64 + kg];
      }
      if (z < 2) {
        #pragma unroll
        for (int i = 0; i < 4; ++i)
          #pragma unroll
          for (int j = 0; j < 4; ++j)
            acc[i][j] = __builtin_amdgcn_mfma_f32_16x16x32_bf16(wf[i], xf[j], acc[i][j], 0, 0, 0);
      } else {
        #pragma unroll
        for (int i = 0; i < 4; ++i)
          #pragma unroll
          for (int j = 0; j < 4; ++j)
            acc[i][j] = __builtin_amdgcn_mfma_f32_16x16x32_bf16(xf[i], wf[j], acc[i][j], 0, 0, 0);
      }
    }
  }

  if (z < 2) {
    unsigned short* O = z == 0 ? Qp : Kp;
    const float osc = z == 0 ? qscale : 1.0f;
    #pragma unroll
    for (int i = 0; i < 4; ++i) {
      const int nb = n0 + wn + i * 16 + 4 * g;
      const float4v bb = *(const float4v*)&bias[nb];
      #pragma unroll
      for (int j = 0; j < 4; ++j) {
        const int m = m0 + wm + j * 16 + l16;
        uint32x2 pk;
        pk[0] = pkbf((acc[i][j][0] + bb[0]) * osc, (acc[i][j][1] + bb[1]) * osc);
        pk[1] = pkbf((acc[i][j][2] + bb[2]) * osc, (acc[i][j][3] + bb[3]) * osc);
        *(uint32x2*)(O + (size_t)m * N + nb) = pk;
      }
    }
  } else {
    #pragma unroll
    for (int j = 0; j < 4; ++j) {
      const int n = n0 + wn + j * 16 + l16;
      const float bb = bias[n];
      #pragma unroll
      for (int i = 0; i < 4; ++i) {
        const int mb = m0 + wm + i * 16 + 4 * g;
        uint32x2 pk;
        pk[0] = pkbf(acc[i][j][0] + bb, acc[i][j][1] + bb);
        pk[1] = pkbf(acc[i][j][2] + bb, acc[i][j][3] + bb);
        *(uint32x2*)(Vt + (size_t)n * M + mb) = pk;
      }
    }
  }
}

// ---------------------------------------------------------------------------
// Flash attention PARTIAL kernel [R7 config: chunk=16, 960 blocks, 4/CU].
// Fixed softmax -> partials additive. PV via K=16 MFMA, P from registers.
// ---------------------------------------------------------------------------
__global__ __launch_bounds__(256, 4) void flash_part(
    const unsigned short* __restrict__ Qp,  // [S][768] bf16, pre-scaled
    const unsigned short* __restrict__ Kp,  // [S][768] bf16
    const unsigned short* __restrict__ Vt,  // [768][S] bf16
    unsigned short* __restrict__ Opart,     // [1536 slots][128][64] bf16
    float* __restrict__ lpart)              // [1536 slots][128] fp32
{
  __shared__ unsigned short lds_k[2][64 * 64];
  __shared__ unsigned short lds_v[2][64 * 64];
  const int S = 4096, DM = 768;

  const int gid = blockIdx.x;
  const int h = gid % 12;
  const int e = 79 - gid / 12;
  int t, c;
  if (e < 8)       { t = e;                c = 0; }
  else if (e < 24) { t = 8 + (e - 8) / 2;  c = (e - 8) % 2; }
  else if (e < 48) { t = 16 + (e - 24) / 3; c = (e - 24) % 3; }
  else             { t = 24 + (e - 48) / 4; c = (e - 48) % 4; }
  const int kb0 = c * 16;
  const int kbe = min(kb0 + 16, 2 * t + 2);

  const int tid = threadIdx.x, wave = tid >> 6, lane = tid & 63;
  const int g = lane >> 4, l16 = lane & 15;
  const int sw = l16 & 7;
  const int qbase = t * 128 + wave * 32;

  short8 qf[2][2];
  #pragma unroll
  for (int qc = 0; qc < 2; ++qc) {
    const unsigned short* qp = Qp + (size_t)(qbase + qc * 16 + l16) * DM + h * 64;
    qf[qc][0] = *(const short8*)(qp + g * 8);
    qf[qc][1] = *(const short8*)(qp + 32 + g * 8);
  }

  float4v o[2][4] = {};
  float lsum[2] = {0.0f, 0.0f};

  const int strow = wave * 16 + (lane >> 3);
  const int skg = lane & 7;

  #pragma unroll
  for (int cc = 0; cc < 2; ++cc) {
    const int row = strow + cc * 8;
    const int kg = skg ^ (row & 7);
    gll16(Kp + (size_t)(kb0 * 64 + row) * DM + h * 64 + kg * 8,
          &lds_k[0][(wave * 16 + cc * 8) * 64]);
    gll16(Vt + (size_t)(h * 64 + row) * S + kb0 * 64 + kg * 8,
          &lds_v[0][(wave * 16 + cc * 8) * 64]);
  }
  __syncthreads();

  for (int kb = kb0; kb < kbe; ++kb) {
    const int cur = kb & 1;
    if (kb + 1 < kbe) {
      const int nb = cur ^ 1;
      #pragma unroll
      for (int cc = 0; cc < 2; ++cc) {
        const int row = strow + cc * 8;
        const int kg = skg ^ (row & 7);
        gll16(Kp + (size_t)((kb + 1) * 64 + row) * DM + h * 64 + kg * 8,
              &lds_k[nb][(wave * 16 + cc * 8) * 64]);
        gll16(Vt + (size_t)(h * 64 + row) * S + (kb + 1) * 64 + kg * 8,
              &lds_v[nb][(wave * 16 + cc * 8) * 64]);
      }
    }
    const unsigned short* kc = lds_k[cur];
    const unsigned short* vc = lds_v[cur];

    // S^T = K * Q^T : 4 key-subtiles x 2 q-columns (K=32 MFMA)
    float4v sf[2][4];
    #pragma unroll
    for (int mt = 0; mt < 4; ++mt) {
      short8 ka0 = *(const short8*)&kc[(mt * 16 + l16) * 64 + ((0 + g) ^ sw) * 8];
      short8 ka1 = *(const short8*)&kc[(mt * 16 + l16) * 64 + ((4 + g) ^ sw) * 8];
      #pragma unroll
      for (int qc = 0; qc < 2; ++qc) {
        float4v a = {};
        a = __builtin_amdgcn_mfma_f32_16x16x32_bf16(ka0, qf[qc][0], a, 0, 0, 0);
        a = __builtin_amdgcn_mfma_f32_16x16x32_bf16(ka1, qf[qc][1], a, 0, 0, 0);
        sf[qc][mt] = a;
      }
    }

    if ((kb + 1) * 64 > qbase) {  // causal mask (wave-uniform trigger)
      #pragma unroll
      for (int qc = 0; qc < 2; ++qc) {
        const int q = qbase + qc * 16 + l16;
        #pragma unroll
        for (int mt = 0; mt < 4; ++mt)
          #pragma unroll
          for (int rr = 0; rr < 4; ++rr) {
            const int key = kb * 64 + mt * 16 + 4 * g + rr;
            sf[qc][mt][rr] = (key <= q) ? sf[qc][mt][rr] : -1e30f;
          }
      }
    }

    // p = exp2(s); pack straight into PV B-fragments (C-layout == B-layout)
    short4v pb[2][4];
    #pragma unroll
    for (int qc = 0; qc < 2; ++qc)
      #pragma unroll
      for (int mt = 0; mt < 4; ++mt) {
        float4v pe;
        #pragma unroll
        for (int rr = 0; rr < 4; ++rr) {
          pe[rr] = fexp2(sf[qc][mt][rr]);
          lsum[qc] += pe[rr];
        }
        union { uint32x2 u; short4v s; } cv;
        cv.u[0] = pkbf(pe[0], pe[1]);
        cv.u[1] = pkbf(pe[2], pe[3]);
        pb[qc][mt] = cv.s;
      }

    // O^T += V^T * P : K=16 MFMAs, A-frag = V^T 4 keys (b64), B = pb (regs)
    #pragma unroll
    for (int ms = 0; ms < 4; ++ms) {
      const int slot = ((2 * ms + (g >> 1)) ^ sw) * 8 + (g & 1) * 4;
      #pragma unroll
      for (int dt = 0; dt < 4; ++dt) {
        short4v va = *(const short4v*)&vc[(dt * 16 + l16) * 64 + slot];
        o[0][dt] = mfma16bf(va, pb[0][ms], o[0][dt]);
        o[1][dt] = mfma16bf(va, pb[1][ms], o[1][dt]);
      }
    }

    __syncthreads();  // drain prefetch DMA + protect buffer reuse
  }

  // epilogue: unnormalized partial write
  const int slot = (h * 32 + t) * 4 + c;
  unsigned short* ob = Opart + (size_t)slot * 8192;
  #pragma unroll
  for (int qc = 0; qc < 2; ++qc) {
    float L = lsum[qc];
    L += __shfl_xor(L, 16);
    L += __shfl_xor(L, 32);
    const int ql = wave * 32 + qc * 16 + l16;
    if (g == 0) lpart[slot * 128 + ql] = L;
    #pragma unroll
    for (int dt = 0; dt < 4; ++dt) {
      uint32x2 ov;
      ov[0] = pkbf(o[qc][dt][0], o[qc][dt][1]);
      ov[1] = pkbf(o[qc][dt][2], o[qc][dt][3]);
      *(uint32x2*)(ob + (size_t)ql * 64 + dt * 16 + 4 * g) = ov;
    }
  }
}

// ---------------------------------------------------------------------------
// Combine partials: AO[q][h*64+d] = sum_c Opart / sum_c lpart. Grid (32, 12).
// ---------------------------------------------------------------------------
__global__ __launch_bounds__(256) void flash_combine(
    const unsigned short* __restrict__ Opart, const float* __restrict__ lpart,
    unsigned short* __restrict__ AO)
{
  const int t = blockIdx.x, h = blockIdx.y;
  const int nc = (2 * t + 17) >> 4;          // ceil((2t+2)/16)
  const int slot0 = (h * 32 + t) * 4;
  const int tid = threadIdx.x;
  const int qr = tid >> 2, dc = (tid & 3) * 16;
  #pragma unroll
  for (int it = 0; it < 2; ++it) {
    const int ql = it * 64 + qr;
    float acc[16];
    #pragma unroll
    for (int j = 0; j < 16; ++j) acc[j] = 0.0f;
    float lsum = 0.0f;
    for (int cc = 0; cc < nc; ++cc) {
      const int slot = slot0 + cc;
      lsum += lpart[slot * 128 + ql];
      const uint32x4* p = (const uint32x4*)(Opart + (size_t)slot * 8192 + ql * 64 + dc);
      uint32x4 w0 = p[0], w1 = p[1];
      #pragma unroll
      for (int j = 0; j < 4; ++j) {
        union { uint32_t u; float f; } lo, hi;
        lo.u = w0[j] << 16; hi.u = w0[j] & 0xffff0000u;
        acc[2 * j] += lo.f; acc[2 * j + 1] += hi.f;
        lo.u = w1[j] << 16; hi.u = w1[j] & 0xffff0000u;
        acc[8 + 2 * j] += lo.f; acc[8 + 2 * j + 1] += hi.f;
      }
    }
    const float inv = 1.0f / lsum;
    uint32x4 o0, o1;
    #pragma unroll
    for (int j = 0; j < 4; ++j) {
      o0[j] = pkbf(acc[2 * j] * inv, acc[2 * j + 1] * inv);
      o1[j] = pkbf(acc[8 + 2 * j] * inv, acc[8 + 2 * j + 1] * inv);
    }
    unsigned short* dst = AO + (size_t)(t * 128 + ql) * 768 + h * 64 + dc;
    *(uint32x4*)dst = o0;
    *(uint32x4*)(dst + 8) = o1;
  }
}

// ---------------------------------------------------------------------------
// Output projection: fp32 out = AO(bf16) * wo^T + bo. 128x128, all-DMA, C^T.
// ---------------------------------------------------------------------------
__global__ __launch_bounds__(256) void gemm_out(
    const unsigned short* __restrict__ A, const unsigned short* __restrict__ W,
    const float* __restrict__ bias, float* __restrict__ Out)
{
  __shared__ unsigned short As[128 * 64];
  __shared__ unsigned short Ws[128 * 64];
  const int N = 768, K = 768;
  const int tid = threadIdx.x, wave = tid >> 6, lane = tid & 63;
  const int g = lane >> 4, l16 = lane & 15;
  const int sw = l16 & 7;
  const int m0 = blockIdx.x * 128, n0 = blockIdx.y * 128;
  const int wn = (wave >> 1) * 64, wm = (wave & 1) * 64;
  const int srow0 = wave * 32 + (lane >> 3);
  const int skg = lane & 7;

  float4v acc[4][4] = {};

  for (int k0 = 0; k0 < K; k0 += 64) {
    if (k0) __syncthreads();
    #pragma unroll
    for (int c = 0; c < 4; ++c) {
      const int row = srow0 + c * 8;
      const int kg = skg ^ (row & 7);
      gll16(A + (size_t)(m0 + row) * K + k0 + kg * 8, &As[(wave * 32 + c * 8) * 64]);
      gll16(W + (size_t)(n0 + row) * K + k0 + kg * 8, &Ws[(wave * 32 + c * 8) * 64]);
    }
    __syncthreads();
    #pragma unroll
    for (int kk = 0; kk < 2; ++kk) {
      const int kg = ((kk * 4 + g) ^ sw) * 8;
      short8 xf[4], wf[4];
      #pragma unroll
      for (int t = 0; t < 4; ++t) {
        xf[t] = *(const short8*)&As[(wm + t * 16 + l16) * 64 + kg];
        wf[t] = *(const short8*)&Ws[(wn + t * 16 + l16) * 64 + kg];
      }
      #pragma unroll
      for (int i = 0; i < 4; ++i)
        #pragma unroll
        for (int j = 0; j < 4; ++j)
          acc[i][j] = __builtin_amdgcn_mfma_f32_16x16x32_bf16(wf[i], xf[j], acc[i][j], 0, 0, 0);
    }
  }

  #pragma unroll
  for (int i = 0; i < 4; ++i) {
    const int nb = n0 + wn + i * 16 + 4 * g;
    const float4v bb = *(const float4v*)&bias[nb];
    #pragma unroll
    for (int j = 0; j < 4; ++j) {
      const int m = m0 + wm + j * 16 + l16;
      float4v ov;
      #pragma unroll
      for (int rr = 0; rr < 4; ++rr) ov[rr] = acc[i][j][rr] + bb[rr];
      *(float4v*)(Out + (size_t)m * N + nb) = ov;
    }
  }
}

extern "C" void kernel_launch(void* const* d_in, const int* in_sizes, int n_in,
                              void* d_out, int out_size, void* d_ws, size_t ws_size,
                              hipStream_t stream) {
  const float* q  = (const float*)d_in[0];
  const float* k  = (const float*)d_in[1];
  const float* v  = (const float*)d_in[2];
  const float* wq = (const float*)d_in[3];
  const float* bq = (const float*)d_in[4];
  const float* wk = (const float*)d_in[5];
  const float* bk = (const float*)d_in[6];
  const float* wv = (const float*)d_in[7];
  const float* bv = (const float*)d_in[8];
  const float* wo = (const float*)d_in[9];
  const float* bo = (const float*)d_in[10];
  float* out = (float*)d_out;

  const int S = 4096, D = 768;
  unsigned short* Qp    = (unsigned short*)d_ws;
  unsigned short* Kp    = Qp  + (size_t)S * D;
  unsigned short* Vt    = Kp  + (size_t)S * D;
  unsigned short* AO    = Vt  + (size_t)S * D;
  unsigned short* wqb   = AO  + (size_t)S * D;
  unsigned short* wkb   = wqb + (size_t)D * D;
  unsigned short* wvb   = wkb + (size_t)D * D;
  unsigned short* wob   = wvb + (size_t)D * D;
  unsigned short* Opart = wob + (size_t)D * D;            // 1536 * 8192 bf16 = 24 MB
  float*          lpart = (float*)(Opart + (size_t)1536 * 8192);  // 1536*128 f32

  CvtArgs ca;
  ca.src[0] = wq; ca.dst[0] = wqb;
  ca.src[1] = wk; ca.dst[1] = wkb;
  ca.src[2] = wv; ca.dst[2] = wvb;
  ca.src[3] = wo; ca.dst[3] = wob;

  const float SC = 0.125f * 1.44269504089f;  // (1/sqrt(64)) * log2(e), folded into Q
  dim3 blk(256);
  cvt_all<<<dim3(1152), blk, 0, stream>>>(ca);
  gemm_qkv<<<dim3(32, 6, 3), blk, 0, stream>>>(q, k, v, wqb, wkb, wvb,
                                               bq, bk, bv, Qp, Kp, Vt, SC);
  flash_part<<<dim3(960), blk, 0, stream>>>(Qp, Kp, Vt, Opart, lpart);
  flash_combine<<<dim3(32, 12), blk, 0, stream>>>(Opart, lpart, AO);
  gemm_out<<<dim3(32, 6), blk, 0, stream>>>(AO, wob, bo, out);
}